// Round 8
// baseline (7492.599 us; speedup 1.0000x reference)
//
#include <hip/hip_runtime.h>
#include <hip/hip_fp16.h>

// Problem constants (from reference)
constexpr int B        = 2;
constexpr int N_IN     = 262144;
constexpr int D        = 32;
constexpr int N_OUT    = 65536;
constexpr int K        = 4;
constexpr int NK       = 9;
constexpr int P        = B * N_OUT * K;        // 524288 output points
constexpr int PPB      = N_OUT * K;            // 262144 points per batch
constexpr size_t XTOT  = (size_t)B * N_IN * D; // 16,777,216 feature elements
constexpr int NPH       = 4;     // feature-table tiles: 65536 rows = 4.2 MB
constexpr int GRID_MAIN = 2048;  // 1 pt/thread; EXACTLY one resident generation

typedef _Float16 half2v __attribute__((ext_vector_type(2)));
typedef _Float16 half4v __attribute__((ext_vector_type(4)));
typedef _Float16 half8v __attribute__((ext_vector_type(8)));
typedef float    f4v    __attribute__((ext_vector_type(4)));

// ---------------- fused pre-pass: fp16 table + packed coords + barrier init -
__global__ __launch_bounds__(256) void prep_kernel(
    const float* __restrict__ x,   _Float16* __restrict__ xh,
    const float* __restrict__ cin, half2v*   __restrict__ cp,
    unsigned int* __restrict__ bar)
{
    const int tid  = blockIdx.x * 256 + threadIdx.x;       // 0 .. 2M-1
    const size_t i = (size_t)tid * 8;
    const f4v a = __builtin_nontemporal_load(reinterpret_cast<const f4v*>(x + i));
    const f4v b = __builtin_nontemporal_load(reinterpret_cast<const f4v*>(x + i) + 1);
    half8v h;
    h[0] = (_Float16)a[0]; h[1] = (_Float16)a[1];
    h[2] = (_Float16)a[2]; h[3] = (_Float16)a[3];
    h[4] = (_Float16)b[0]; h[5] = (_Float16)b[1];
    h[6] = (_Float16)b[2]; h[7] = (_Float16)b[3];
    *reinterpret_cast<half8v*>(xh + i) = h;
    if (tid < B * N_IN) {
        half2v c;
        c[0] = (_Float16)cin[tid];
        c[1] = (_Float16)cin[B * N_IN + tid];
        cp[tid] = c;
    }
    if (blockIdx.x == 0 && threadIdx.x < NPH)   // re-zero convoy barrier every
        __hip_atomic_store(bar + threadIdx.x, 0u,  // launch (graph replays!)
                           __ATOMIC_RELAXED, __HIP_MEMORY_SCOPE_AGENT);
}

// ---------------- non-uniform-sigma correctness path (not hit by bench) ------
__device__ void slow_point(
    int p, int cbase, const _Float16* __restrict__ xb,
    const half2v* __restrict__ cpack, const float* __restrict__ coords_out,
    const float* __restrict__ sigma, const int* __restrict__ nidx,
    float* __restrict__ out)
{
    const float cox = coords_out[p];
    const float coy = coords_out[P + p];
    const int* __restrict__ ip = nidx + (size_t)p * NK;
    int id[NK]; float d2[NK];
    #pragma unroll
    for (int t = 0; t < NK; ++t) id[t] = ip[t];
    #pragma unroll
    for (int t = 0; t < NK; ++t) {
        const half2v c = cpack[cbase + id[t]];
        const float dx = cox - (float)c[0], dy = coy - (float)c[1];
        d2[t] = dx * dx + dy * dy;
    }
    for (int q = 0; q < 4; ++q) {
        float n[8], d[8], s[8];
        #pragma unroll
        for (int k = 0; k < 8; ++k) {
            n[k] = 0.f; d[k] = 0.f;
            const float g = sigma[q * 8 + k];
            s[k] = 1.0f / (2.0f * g * g);
        }
        #pragma unroll
        for (int t = 0; t < NK; ++t) {
            const half8v f = *reinterpret_cast<const half8v*>(xb + id[t] * D + q * 8);
            #pragma unroll
            for (int k = 0; k < 8; ++k) {
                const float w = __expf(-d2[t] * s[k]);
                n[k] += w * (float)f[k];
                d[k] += w;
            }
        }
        #pragma unroll
        for (int k = 0; k < 8; ++k)
            out[(size_t)p * D + q * 8 + k] = n[k] / (d[k] + 1e-9f);
    }
}

// ---------------- main kernel: single-generation convoy, LDS accumulators ----
// 2048 blocks x 256 threads = exactly P threads = exactly one fully-resident
// generation (r7 lesson: any larger grid backfills into a phase-mixed steady
// state -> zero locality). 1 point/thread; the 32-channel fp16 accumulator
// lives in a PRIVATE LDS row (64 B/thread, 16 KB/block, 8 blocks/CU = 128 KB)
// -> persistent registers ~30 (idx[9], w[9], den) -> no spill (r2/r3/r4/r6
// all spilled holding accumulators in VGPRs). No cross-thread LDS sharing, so
// no sync needed for correctness; __syncthreads + bounded-spin global barrier
// only pace the 4 feature-table tiles (4.2 MB ~ one XCD L2) for L2 locality
// (r3: convoy collapsed FETCH 271->108 MB).
// LDS layout: [pt][32ch] with 8B-slot XOR swizzle ps = s ^ ((t>>1)&7)
// -> 4-way bank conflict on ds b64 RMW (1.58x, overlapped) vs 32-way naive.
__global__ __launch_bounds__(256) void projection_ldsacc_kernel(
    const _Float16* __restrict__ xh,         // (B, N_IN, D) fp16
    const half2v*   __restrict__ cpack,      // (B, N_IN) fp16 pairs
    const float*    __restrict__ coords_out, // (2, P)
    const float*    __restrict__ sigma,      // (D,)
    const int*      __restrict__ nidx,       // (P, NK)
    float*          __restrict__ out,        // (P, D)
    unsigned int*   __restrict__ bar)        // (NPH,) convoy barrier
{
    __shared__ _Float16 acc[256 * 32];       // 16 KB; thread t owns acc[t*32..]

    const int t     = threadIdx.x;
    const int bid   = blockIdx.x;            // 0..2047
    const int xcd   = bid & 7;
    const int batch = xcd >> 2;              // one batch per XCD half
    const int wb    = (bid >> 3) * 4 + (xcd & 3);   // 0..1023 within batch
    const int p     = batch * PPB + wb * 256 + t;
    const int cbase = batch * N_IN;
    const _Float16* __restrict__ xb = xh + (size_t)cbase * D;

    float s0; bool uni = true;
    {
        const float g = sigma[0];
        s0 = 1.0f / (2.0f * g * g);
        for (int k = 1; k < 32; ++k) uni = uni && (sigma[k] == sigma[0]);
    }
    if (!uni) {   // grid-uniform branch: no block ever reaches the barrier
        slow_point(p, cbase, xb, cpack, coords_out, sigma, nidx, out);
        return;
    }

    // ---- setup: idx, weights, den (phase-independent) ----
    int   idx[NK];
    float w[NK];
    float den = 0.f;
    {
        const float cox = __builtin_nontemporal_load(coords_out + p);
        const float coy = __builtin_nontemporal_load(coords_out + P + p);
        const int* __restrict__ ip = nidx + (size_t)p * NK;
        #pragma unroll
        for (int tt = 0; tt < NK; ++tt)
            idx[tt] = __builtin_nontemporal_load(ip + tt);
        #pragma unroll
        for (int tt = 0; tt < NK; ++tt) {
            const half2v c = cpack[cbase + idx[tt]];
            const float dx = cox - (float)c[0], dy = coy - (float)c[1];
            w[tt] = __expf(-(dx * dx + dy * dy) * s0);
            den += w[tt];
        }
    }

    // ---- zero my private accumulator row ----
    const int tbase = t * 32;
    const int rot   = (t >> 1) & 7;          // 8B-slot swizzle
    {
        const half4v z = {};
        #pragma unroll
        for (int s = 0; s < 8; ++s)
            *reinterpret_cast<half4v*>(&acc[tbase + s * 4]) = z;
    }

    // ---- phase-tiled gathers: tile = idx>>16 (65536 rows = 4.2 MB) ----
    for (int ph = 0; ph < NPH; ++ph) {
        #pragma unroll
        for (int tt = 0; tt < NK; ++tt) {
            if ((idx[tt] >> 16) == ph) {
                const half8v* fp = reinterpret_cast<const half8v*>(
                    xb + (size_t)idx[tt] * D);
                const _Float16 wh = (_Float16)w[tt];
                half4v wv;
                wv[0] = wh; wv[1] = wh; wv[2] = wh; wv[3] = wh;
                #pragma unroll
                for (int c = 0; c < 4; ++c) {
                    const half8v f  = fp[c];
                    const half4v lo = __builtin_shufflevector(f, f, 0, 1, 2, 3);
                    const half4v hi = __builtin_shufflevector(f, f, 4, 5, 6, 7);
                    const int ps0 = (2 * c)     ^ rot;
                    const int ps1 = (2 * c + 1) ^ rot;
                    half4v* a0 = reinterpret_cast<half4v*>(&acc[tbase + ps0 * 4]);
                    half4v* a1 = reinterpret_cast<half4v*>(&acc[tbase + ps1 * 4]);
                    *a0 += wv * lo;
                    *a1 += wv * hi;
                }
            }
        }
        // ---- convoy barrier (pacing only — no data crosses; bounded spin) --
        if (ph != NPH - 1) {
            __syncthreads();
            if (t == 0) {
                __hip_atomic_fetch_add(bar + ph, 1u,
                                       __ATOMIC_RELAXED, __HIP_MEMORY_SCOPE_AGENT);
                int spins = 0;
                while (__hip_atomic_load(bar + ph, __ATOMIC_RELAXED,
                                         __HIP_MEMORY_SCOPE_AGENT)
                           < (unsigned)GRID_MAIN && spins < 16384) {
                    __builtin_amdgcn_s_sleep(1);
                    ++spins;
                }
            }
            __syncthreads();
        }
    }

    // ---- epilogue: LDS fp16 num -> fp32, divide, NT store (128 B/thread) ---
    const float r = 1.0f / (den + 1e-9f);
    float* op = out + (size_t)p * D;
    #pragma unroll
    for (int s = 0; s < 8; ++s) {
        const int ps = s ^ rot;
        const half4v v = *reinterpret_cast<const half4v*>(&acc[tbase + ps * 4]);
        f4v o;
        o[0] = (float)v[0] * r; o[1] = (float)v[1] * r;
        o[2] = (float)v[2] * r; o[3] = (float)v[3] * r;
        __builtin_nontemporal_store(o, reinterpret_cast<f4v*>(op) + s);
    }
}

// ---------------- fallback: proven fp32 path (if ws too small) ---------------
__global__ __launch_bounds__(256) void projection_kernel_f32(
    const float* __restrict__ x,
    const float* __restrict__ coords_in,
    const float* __restrict__ coords_out,
    const float* __restrict__ sigma,
    const int*   __restrict__ nidx,
    float*       __restrict__ out)
{
    const int tid   = blockIdx.x * 256 + threadIdx.x;
    const int point = tid >> 3;
    const int q     = tid & 7;
    const int b     = point / PPB;
    const int cbase = b * N_IN;

    const float cox = coords_out[point];
    const float coy = coords_out[P + point];

    const float4 sg = *reinterpret_cast<const float4*>(sigma + q * 4);
    const float s0 = 1.0f / (2.0f * sg.x * sg.x);
    const float s1 = 1.0f / (2.0f * sg.y * sg.y);
    const float s2 = 1.0f / (2.0f * sg.z * sg.z);
    const float s3 = 1.0f / (2.0f * sg.w * sg.w);

    float4 num = make_float4(0.f, 0.f, 0.f, 0.f);
    float4 den = make_float4(0.f, 0.f, 0.f, 0.f);
    const int* __restrict__ ip = nidx + (size_t)point * NK;

    #pragma unroll
    for (int nk = 0; nk < NK; ++nk) {
        const int idx = ip[nk];
        const float cx = coords_in[cbase + idx];
        const float cy = coords_in[B * N_IN + cbase + idx];
        const float dx = cox - cx;
        const float dy = coy - cy;
        const float d2 = dx * dx + dy * dy;
        const float4 f = *reinterpret_cast<const float4*>(
            x + (size_t)(cbase + idx) * D + q * 4);
        const float w0 = __expf(-d2 * s0);
        const float w1 = __expf(-d2 * s1);
        const float w2 = __expf(-d2 * s2);
        const float w3 = __expf(-d2 * s3);
        num.x += w0 * f.x;  den.x += w0;
        num.y += w1 * f.y;  den.y += w1;
        num.z += w2 * f.z;  den.z += w2;
        num.w += w3 * f.w;  den.w += w3;
    }

    float4 o;
    o.x = num.x / (den.x + 1e-9f);
    o.y = num.y / (den.y + 1e-9f);
    o.z = num.z / (den.z + 1e-9f);
    o.w = num.w / (den.w + 1e-9f);
    *reinterpret_cast<float4*>(out + (size_t)point * D + q * 4) = o;
}

extern "C" void kernel_launch(void* const* d_in, const int* in_sizes, int n_in,
                              void* d_out, int out_size, void* d_ws, size_t ws_size,
                              hipStream_t stream) {
    const float* x      = (const float*)d_in[0];
    const float* cin    = (const float*)d_in[1];
    const float* cout_  = (const float*)d_in[2];
    const float* sigma  = (const float*)d_in[3];
    const int*   nidx   = (const int*)  d_in[4];
    float*       outp   = (float*)d_out;

    const int block = 256;

    const size_t xh_bytes = XTOT * sizeof(_Float16);            // 33.55 MB
    const size_t cp_bytes = (size_t)B * N_IN * sizeof(half2v);  //  2.10 MB

    if (ws_size >= xh_bytes + cp_bytes + 64) {
        _Float16*     xh  = (_Float16*)d_ws;
        half2v*       cp  = (half2v*)((char*)d_ws + xh_bytes);
        unsigned int* bar = (unsigned int*)((char*)d_ws + xh_bytes + cp_bytes);
        prep_kernel<<<(int)(XTOT / 8 / block), block, 0, stream>>>(
            x, xh, cin, cp, bar);
        projection_ldsacc_kernel<<<GRID_MAIN, block, 0, stream>>>(
            xh, cp, cout_, sigma, nidx, outp, bar);
    } else {
        const int grid_main = (P * 8) / block;   // 16384
        projection_kernel_f32<<<grid_main, block, 0, stream>>>(
            x, cin, cout_, sigma, nidx, outp);
    }
}

// Round 9
// 804.194 us; speedup vs baseline: 9.3169x; 9.3169x over previous
//
#include <hip/hip_runtime.h>
#include <hip/hip_fp16.h>

// Problem constants (from reference)
constexpr int B        = 2;
constexpr int N_IN     = 262144;
constexpr int D        = 32;
constexpr int N_OUT    = 65536;
constexpr int K        = 4;
constexpr int NK       = 9;
constexpr int P        = B * N_OUT * K;        // 524288 output points
constexpr int PPB      = N_OUT * K;            // 262144 points per batch
constexpr size_t XTOT  = (size_t)B * N_IN * D; // 16,777,216 feature elements
constexpr int NPH       = 4;     // feature-table tiles: 65536 rows = 4.2 MB
constexpr int GRID_MAIN = 1024;  // == measured residency at 64 VGPR (4 blk/CU)
constexpr int ITERS     = 8;     // 1024 blk x 64 pts x 8 iters = P points

typedef _Float16 half2v __attribute__((ext_vector_type(2)));
typedef _Float16 half8v __attribute__((ext_vector_type(8)));
typedef float    f4v    __attribute__((ext_vector_type(4)));

// Quad broadcast via DPP quad_perm: all 4 lanes of a quad get lane L's value.
template<int L>
__device__ __forceinline__ int qbcast_i(int v) {
    return __builtin_amdgcn_mov_dpp(v, L * 0x55, 0xf, 0xf, true);
}
template<int L>
__device__ __forceinline__ float qbcast_f(float v) {
    return __int_as_float(
        __builtin_amdgcn_mov_dpp(__float_as_int(v), L * 0x55, 0xf, 0xf, true));
}

// ---------------- fused pre-pass: fp16 table + packed coords + fence init ---
__global__ __launch_bounds__(256) void prep_kernel(
    const float* __restrict__ x,   _Float16* __restrict__ xh,
    const float* __restrict__ cin, half2v*   __restrict__ cp,
    unsigned int* __restrict__ bar)
{
    const int tid  = blockIdx.x * 256 + threadIdx.x;       // 0 .. 2M-1
    const size_t i = (size_t)tid * 8;
    const f4v a = __builtin_nontemporal_load(reinterpret_cast<const f4v*>(x + i));
    const f4v b = __builtin_nontemporal_load(reinterpret_cast<const f4v*>(x + i) + 1);
    half8v h;
    h[0] = (_Float16)a[0]; h[1] = (_Float16)a[1];
    h[2] = (_Float16)a[2]; h[3] = (_Float16)a[3];
    h[4] = (_Float16)b[0]; h[5] = (_Float16)b[1];
    h[6] = (_Float16)b[2]; h[7] = (_Float16)b[3];
    *reinterpret_cast<half8v*>(xh + i) = h;
    if (tid < B * N_IN) {
        half2v c;
        c[0] = (_Float16)cin[tid];
        c[1] = (_Float16)cin[B * N_IN + tid];
        cp[tid] = c;
    }
    if (blockIdx.x == 0 && threadIdx.x < ITERS)  // re-zero fences every launch
        __hip_atomic_store(bar + threadIdx.x, 0u,   // (graph replays!)
                           __ATOMIC_RELAXED, __HIP_MEMORY_SCOPE_AGENT);
}

// ---------------- non-uniform-sigma correctness path (not hit by bench) ------
__device__ void slow_point(
    int p, int cbase, const _Float16* __restrict__ xb,
    const half2v* __restrict__ cpack, const float* __restrict__ coords_out,
    const float* __restrict__ sigma, const int* __restrict__ nidx,
    float* __restrict__ out)
{
    const float cox = coords_out[p];
    const float coy = coords_out[P + p];
    const int* __restrict__ ip = nidx + (size_t)p * NK;
    int id[NK]; float d2[NK];
    #pragma unroll
    for (int t = 0; t < NK; ++t) id[t] = ip[t];
    #pragma unroll
    for (int t = 0; t < NK; ++t) {
        const half2v c = cpack[cbase + id[t]];
        const float dx = cox - (float)c[0], dy = coy - (float)c[1];
        d2[t] = dx * dx + dy * dy;
    }
    for (int q = 0; q < 4; ++q) {
        float n[8], d[8], s[8];
        #pragma unroll
        for (int k = 0; k < 8; ++k) {
            n[k] = 0.f; d[k] = 0.f;
            const float g = sigma[q * 8 + k];
            s[k] = 1.0f / (2.0f * g * g);
        }
        #pragma unroll
        for (int t = 0; t < NK; ++t) {
            const half8v f = *reinterpret_cast<const half8v*>(xb + id[t] * D + q * 8);
            #pragma unroll
            for (int k = 0; k < 8; ++k) {
                const float w = __expf(-d2[t] * s[k]);
                n[k] += w * (float)f[k];
                d[k] += w;
            }
        }
        #pragma unroll
        for (int k = 0; k < 8; ++k)
            out[(size_t)p * D + q * 8 + k] = n[k] / (d[k] + 1e-9f);
    }
}

// ---------------- main kernel: persistent single-generation convoy -----------
// 1024 blocks x 256 threads = the MEASURED resident population at 64 VGPR
// (4 blocks/CU; r3 proved this grid's global fence fills). Body = r7's proven
// spill-free 4-lane structure (44 VGPR, WRITE 76 MB). Outer loop: 8 iters x
// 64 points/block; inside each iter the 9 gathers sweep 4 feature-table tiles
// of 4.2 MB (~one XCD L2) with __syncthreads pacing; a bounded per-iteration
// fence (cap 512 spins — r8 lesson: pathology cost = cap x grid) stops drift.
// No backfill (persistent) -> no r7-style phase mixing.
__global__ __launch_bounds__(256) void projection_conv_kernel(
    const _Float16* __restrict__ xh,         // (B, N_IN, D) fp16
    const half2v*   __restrict__ cpack,      // (B, N_IN) fp16 pairs
    const float*    __restrict__ coords_out, // (2, P)
    const float*    __restrict__ sigma,      // (D,)
    const int*      __restrict__ nidx,       // (P, NK)
    float*          __restrict__ out,        // (P, D)
    unsigned int*   __restrict__ bar)        // (ITERS,) iteration fences
{
    const int bid   = blockIdx.x;            // 0..1023
    const int xcd   = bid & 7;
    const int batch = xcd >> 2;              // one batch per XCD half
    const int wbase = (bid >> 3) * 4 + (xcd & 3);   // 0..511 within batch
    const int h     = threadIdx.x & 3;       // channel octet: 8h..8h+7
    const int cbase = batch * N_IN;

    const float4 sg0 = *reinterpret_cast<const float4*>(sigma + h * 8);
    const float4 sg1 = *reinterpret_cast<const float4*>(sigma + h * 8 + 4);
    float s[8];
    s[0] = 1.0f / (2.0f * sg0.x * sg0.x); s[1] = 1.0f / (2.0f * sg0.y * sg0.y);
    s[2] = 1.0f / (2.0f * sg0.z * sg0.z); s[3] = 1.0f / (2.0f * sg0.w * sg0.w);
    s[4] = 1.0f / (2.0f * sg1.x * sg1.x); s[5] = 1.0f / (2.0f * sg1.y * sg1.y);
    s[6] = 1.0f / (2.0f * sg1.z * sg1.z); s[7] = 1.0f / (2.0f * sg1.w * sg1.w);
    bool uni = true;
    #pragma unroll
    for (int k = 1; k < 8; ++k) uni = uni && (s[k] == s[0]);
    // s[0] is h-dependent; check grid-uniformity across all 32 channels:
    {
        const float g0 = sigma[0];
        const float ss = 1.0f / (2.0f * g0 * g0);
        uni = uni && (s[0] == ss);
    }

    if (!uni) {   // grid-uniform branch: no block ever touches the fence
        if (h == 0) {
            for (int jj = 0; jj < ITERS; ++jj) {
                const int p = batch * PPB + wbase * 512 + jj * 64 +
                              (threadIdx.x >> 2);
                slow_point(p, cbase, xh + (size_t)cbase * D, cpack,
                           coords_out, sigma, nidx, out);
            }
        }
        return;
    }
    const float s0 = s[0];

    for (int jj = 0; jj < ITERS; ++jj) {
        const int point = batch * PPB + wbase * 512 + jj * 64 + (threadIdx.x >> 2);

        const float cox = __builtin_nontemporal_load(coords_out + point);
        const float coy = __builtin_nontemporal_load(coords_out + P + point);

        // ---- cooperative idx load: lane h owns t=h,4+h; t=8 shared ----
        const int* __restrict__ ip = nidx + (size_t)point * NK;
        const int ia = __builtin_nontemporal_load(ip + h);
        const int ib = __builtin_nontemporal_load(ip + 4 + h);
        const int i8 = __builtin_nontemporal_load(ip + 8);

        const half2v ca = cpack[cbase + ia];
        const half2v cb = cpack[cbase + ib];
        const half2v c8 = cpack[cbase + i8];

        int idxs[NK];
        idxs[0] = qbcast_i<0>(ia); idxs[1] = qbcast_i<1>(ia);
        idxs[2] = qbcast_i<2>(ia); idxs[3] = qbcast_i<3>(ia);
        idxs[4] = qbcast_i<0>(ib); idxs[5] = qbcast_i<1>(ib);
        idxs[6] = qbcast_i<2>(ib); idxs[7] = qbcast_i<3>(ib);
        idxs[8] = i8;

        const float dxa = cox - (float)ca[0], dya = coy - (float)ca[1];
        const float dxb = cox - (float)cb[0], dyb = coy - (float)cb[1];
        const float dx8 = cox - (float)c8[0], dy8 = coy - (float)c8[1];

        const float wa = __expf(-(dxa * dxa + dya * dya) * s0);
        const float wb = __expf(-(dxb * dxb + dyb * dyb) * s0);
        const float w8 = __expf(-(dx8 * dx8 + dy8 * dy8) * s0);
        float w[NK];
        w[0] = qbcast_f<0>(wa); w[1] = qbcast_f<1>(wa);
        w[2] = qbcast_f<2>(wa); w[3] = qbcast_f<3>(wa);
        w[4] = qbcast_f<0>(wb); w[5] = qbcast_f<1>(wb);
        w[6] = qbcast_f<2>(wb); w[7] = qbcast_f<3>(wb);
        w[8] = w8;
        float den = 0.f;
        #pragma unroll
        for (int t = 0; t < NK; ++t) den += w[t];

        float num[8];
        #pragma unroll
        for (int k = 0; k < 8; ++k) num[k] = 0.f;

        // ---- phase-tiled gathers: tile = idx>>16 (65536 rows = 4.2 MB) ----
        for (int ph = 0; ph < NPH; ++ph) {
            #pragma unroll
            for (int t = 0; t < NK; ++t) {
                if ((idxs[t] >> 16) == ph) {
                    const half8v f = *reinterpret_cast<const half8v*>(
                        xh + (size_t)(cbase + idxs[t]) * D + h * 8);
                    #pragma unroll
                    for (int k = 0; k < 8; ++k) num[k] += w[t] * (float)f[k];
                }
            }
            if (ph != NPH - 1) __syncthreads();  // intra-block phase pacing
        }

        float* op = out + (size_t)point * D + h * 8;
        const float r = 1.0f / (den + 1e-9f);
        f4v o0, o1;
        o0[0] = num[0] * r; o0[1] = num[1] * r;
        o0[2] = num[2] * r; o0[3] = num[3] * r;
        o1[0] = num[4] * r; o1[1] = num[5] * r;
        o1[2] = num[6] * r; o1[3] = num[7] * r;
        __builtin_nontemporal_store(o0, reinterpret_cast<f4v*>(op));
        __builtin_nontemporal_store(o1, reinterpret_cast<f4v*>(op + 4));

        // ---- per-iteration fence: bounded spin, all 1024 blocks resident --
        if (jj != ITERS - 1) {
            __syncthreads();
            if (threadIdx.x == 0) {
                __hip_atomic_fetch_add(bar + jj, 1u,
                                       __ATOMIC_RELAXED, __HIP_MEMORY_SCOPE_AGENT);
                int spins = 0;
                while (__hip_atomic_load(bar + jj, __ATOMIC_RELAXED,
                                         __HIP_MEMORY_SCOPE_AGENT)
                           < (unsigned)GRID_MAIN && spins < 512) {
                    __builtin_amdgcn_s_sleep(2);
                    ++spins;
                }
            }
            __syncthreads();
        }
    }
}

// ---------------- fallback: proven fp32 path (if ws too small) ---------------
__global__ __launch_bounds__(256) void projection_kernel_f32(
    const float* __restrict__ x,
    const float* __restrict__ coords_in,
    const float* __restrict__ coords_out,
    const float* __restrict__ sigma,
    const int*   __restrict__ nidx,
    float*       __restrict__ out)
{
    const int tid   = blockIdx.x * 256 + threadIdx.x;
    const int point = tid >> 3;
    const int q     = tid & 7;
    const int b     = point / PPB;
    const int cbase = b * N_IN;

    const float cox = coords_out[point];
    const float coy = coords_out[P + point];

    const float4 sg = *reinterpret_cast<const float4*>(sigma + q * 4);
    const float s0 = 1.0f / (2.0f * sg.x * sg.x);
    const float s1 = 1.0f / (2.0f * sg.y * sg.y);
    const float s2 = 1.0f / (2.0f * sg.z * sg.z);
    const float s3 = 1.0f / (2.0f * sg.w * sg.w);

    float4 num = make_float4(0.f, 0.f, 0.f, 0.f);
    float4 den = make_float4(0.f, 0.f, 0.f, 0.f);
    const int* __restrict__ ip = nidx + (size_t)point * NK;

    #pragma unroll
    for (int nk = 0; nk < NK; ++nk) {
        const int idx = ip[nk];
        const float cx = coords_in[cbase + idx];
        const float cy = coords_in[B * N_IN + cbase + idx];
        const float dx = cox - cx;
        const float dy = coy - cy;
        const float d2 = dx * dx + dy * dy;
        const float4 f = *reinterpret_cast<const float4*>(
            x + (size_t)(cbase + idx) * D + q * 4);
        const float w0 = __expf(-d2 * s0);
        const float w1 = __expf(-d2 * s1);
        const float w2 = __expf(-d2 * s2);
        const float w3 = __expf(-d2 * s3);
        num.x += w0 * f.x;  den.x += w0;
        num.y += w1 * f.y;  den.y += w1;
        num.z += w2 * f.z;  den.z += w2;
        num.w += w3 * f.w;  den.w += w3;
    }

    float4 o;
    o.x = num.x / (den.x + 1e-9f);
    o.y = num.y / (den.y + 1e-9f);
    o.z = num.z / (den.z + 1e-9f);
    o.w = num.w / (den.w + 1e-9f);
    *reinterpret_cast<float4*>(out + (size_t)point * D + q * 4) = o;
}

extern "C" void kernel_launch(void* const* d_in, const int* in_sizes, int n_in,
                              void* d_out, int out_size, void* d_ws, size_t ws_size,
                              hipStream_t stream) {
    const float* x      = (const float*)d_in[0];
    const float* cin    = (const float*)d_in[1];
    const float* cout_  = (const float*)d_in[2];
    const float* sigma  = (const float*)d_in[3];
    const int*   nidx   = (const int*)  d_in[4];
    float*       outp   = (float*)d_out;

    const int block = 256;

    const size_t xh_bytes = XTOT * sizeof(_Float16);            // 33.55 MB
    const size_t cp_bytes = (size_t)B * N_IN * sizeof(half2v);  //  2.10 MB

    if (ws_size >= xh_bytes + cp_bytes + 64) {
        _Float16*     xh  = (_Float16*)d_ws;
        half2v*       cp  = (half2v*)((char*)d_ws + xh_bytes);
        unsigned int* bar = (unsigned int*)((char*)d_ws + xh_bytes + cp_bytes);
        prep_kernel<<<(int)(XTOT / 8 / block), block, 0, stream>>>(
            x, xh, cin, cp, bar);
        projection_conv_kernel<<<GRID_MAIN, block, 0, stream>>>(
            xh, cp, cout_, sigma, nidx, outp, bar);
    } else {
        const int grid_main = (P * 8) / block;   // 16384
        projection_kernel_f32<<<grid_main, block, 0, stream>>>(
            x, cin, cout_, sigma, nidx, outp);
    }
}

// Round 10
// 215.688 us; speedup vs baseline: 34.7381x; 3.7285x over previous
//
#include <hip/hip_runtime.h>
#include <hip/hip_fp16.h>

// Problem constants (from reference)
constexpr int B        = 2;
constexpr int N_IN     = 262144;
constexpr int D        = 32;
constexpr int N_OUT    = 65536;
constexpr int K        = 4;
constexpr int NK       = 9;
constexpr int P        = B * N_OUT * K;        // 524288 output points
constexpr int PPB      = N_OUT * K;            // 262144 points per batch
constexpr size_t XTOT  = (size_t)B * N_IN * D; // 16,777,216 feature elements

typedef _Float16 half2v __attribute__((ext_vector_type(2)));
typedef _Float16 half8v __attribute__((ext_vector_type(8)));
typedef float    f4v    __attribute__((ext_vector_type(4)));

// Quad broadcast via DPP quad_perm: all 4 lanes of a quad get lane L's value.
template<int L>
__device__ __forceinline__ int qbcast_i(int v) {
    return __builtin_amdgcn_mov_dpp(v, L * 0x55, 0xf, 0xf, true);
}
template<int L>
__device__ __forceinline__ float qbcast_f(float v) {
    return __int_as_float(
        __builtin_amdgcn_mov_dpp(__float_as_int(v), L * 0x55, 0xf, 0xf, true));
}

// ---------------- fused pre-pass: fp16 feature table + packed fp16 coords ---
// (proven in r2-r9; one launch instead of two)
__global__ __launch_bounds__(256) void prep_kernel(
    const float* __restrict__ x,   _Float16* __restrict__ xh,
    const float* __restrict__ cin, half2v*   __restrict__ cp)
{
    const int tid  = blockIdx.x * 256 + threadIdx.x;       // 0 .. 2M-1
    const size_t i = (size_t)tid * 8;
    const f4v a = __builtin_nontemporal_load(reinterpret_cast<const f4v*>(x + i));
    const f4v b = __builtin_nontemporal_load(reinterpret_cast<const f4v*>(x + i) + 1);
    half8v h;
    h[0] = (_Float16)a[0]; h[1] = (_Float16)a[1];
    h[2] = (_Float16)a[2]; h[3] = (_Float16)a[3];
    h[4] = (_Float16)b[0]; h[5] = (_Float16)b[1];
    h[6] = (_Float16)b[2]; h[7] = (_Float16)b[3];
    *reinterpret_cast<half8v*>(xh + i) = h;
    if (tid < B * N_IN) {
        half2v c;
        c[0] = (_Float16)cin[tid];
        c[1] = (_Float16)cin[B * N_IN + tid];
        cp[tid] = c;
    }
}

// ---------------- main kernel (r1 structure — best measured: 89.4 us) --------
// 4 lanes per point; each lane owns 8 channels via one 16 B half8 load, so a
// quad consumes exactly the 64 B feature row it fetches (no spatial waste).
// Quad-redundant idx/coord/exp work deduped via DPP quad_perm broadcasts.
// Traffic-bound: 341 MB (236 gather fetch + 35 streams + 70 write) at
// ~3.8 TB/s random-64B-mix effective BW. Convoy/tiling lines (r2-r9) all
// regressed: locality needs block-level lockstep the scheduler won't give.
__global__ __launch_bounds__(256) void projection_kernel_h(
    const _Float16* __restrict__ xh,         // (B, N_IN, D) fp16
    const half2v*   __restrict__ cpack,      // (B, N_IN) fp16 pairs
    const float*    __restrict__ coords_out, // (2, P)
    const float*    __restrict__ sigma,      // (D,)
    const int*      __restrict__ nidx,       // (P, NK)
    float*          __restrict__ out)        // (P, D)
{
    const int bid   = blockIdx.x;            // 0..8191
    const int xcd   = bid & 7;
    const int j     = bid >> 3;
    const int batch = xcd >> 2;                       // 0 or 1
    const int bbi   = j * 4 + (xcd & 3);              // 0..4095 within batch
    const int point = batch * PPB + bbi * 64 + (threadIdx.x >> 2);
    const int h     = threadIdx.x & 3;                // channel octet: 8h..8h+7

    const int cbase = batch * N_IN;

    const float cox = __builtin_nontemporal_load(coords_out + point);
    const float coy = __builtin_nontemporal_load(coords_out + P + point);

    const float4 sg0 = *reinterpret_cast<const float4*>(sigma + h * 8);
    const float4 sg1 = *reinterpret_cast<const float4*>(sigma + h * 8 + 4);
    float s[8];
    s[0] = 1.0f / (2.0f * sg0.x * sg0.x); s[1] = 1.0f / (2.0f * sg0.y * sg0.y);
    s[2] = 1.0f / (2.0f * sg0.z * sg0.z); s[3] = 1.0f / (2.0f * sg0.w * sg0.w);
    s[4] = 1.0f / (2.0f * sg1.x * sg1.x); s[5] = 1.0f / (2.0f * sg1.y * sg1.y);
    s[6] = 1.0f / (2.0f * sg1.z * sg1.z); s[7] = 1.0f / (2.0f * sg1.w * sg1.w);
    bool uni = true;
    #pragma unroll
    for (int k = 1; k < 8; ++k) uni = uni && (s[k] == s[0]);

    // ---- cooperative idx load: lane h owns t=h and t=4+h; t=8 is shared ----
    const int* __restrict__ ip = nidx + (size_t)point * NK;
    const int ia = __builtin_nontemporal_load(ip + h);       // t = h
    const int ib = __builtin_nontemporal_load(ip + 4 + h);   // t = 4+h
    const int i8 = __builtin_nontemporal_load(ip + 8);       // t = 8 (uniform)

    // ---- cooperative coord gathers (2 per lane + 1 quad-uniform) ----
    const half2v ca = cpack[cbase + ia];
    const half2v cb = cpack[cbase + ib];
    const half2v c8 = cpack[cbase + i8];

    // ---- broadcast idx to all lanes of the quad (8 DPP ops) ----
    int idxs[NK];
    idxs[0] = qbcast_i<0>(ia); idxs[1] = qbcast_i<1>(ia);
    idxs[2] = qbcast_i<2>(ia); idxs[3] = qbcast_i<3>(ia);
    idxs[4] = qbcast_i<0>(ib); idxs[5] = qbcast_i<1>(ib);
    idxs[6] = qbcast_i<2>(ib); idxs[7] = qbcast_i<3>(ib);
    idxs[8] = i8;

    // ---- feature gathers: 9 x 16 B per lane (the real payload) ----
    half8v f[NK];
    #pragma unroll
    for (int t = 0; t < NK; ++t)
        f[t] = *reinterpret_cast<const half8v*>(
            xh + (size_t)(cbase + idxs[t]) * D + h * 8);

    // ---- per-lane distances for owned t's ----
    const float dxa = cox - (float)ca[0], dya = coy - (float)ca[1];
    const float dxb = cox - (float)cb[0], dyb = coy - (float)cb[1];
    const float dx8 = cox - (float)c8[0], dy8 = coy - (float)c8[1];
    const float d2a = dxa * dxa + dya * dya;
    const float d2b = dxb * dxb + dyb * dyb;
    const float d28 = dx8 * dx8 + dy8 * dy8;

    float num[8];
    #pragma unroll
    for (int k = 0; k < 8; ++k) num[k] = 0.f;
    float den[8];
    #pragma unroll
    for (int k = 0; k < 8; ++k) den[k] = 0.f;

    if (uni) {
        // each lane computes only its 2 exps (+ shared t=8), broadcasts w
        const float wa = __expf(-d2a * s[0]);
        const float wb = __expf(-d2b * s[0]);
        const float w8 = __expf(-d28 * s[0]);
        float w[NK];
        w[0] = qbcast_f<0>(wa); w[1] = qbcast_f<1>(wa);
        w[2] = qbcast_f<2>(wa); w[3] = qbcast_f<3>(wa);
        w[4] = qbcast_f<0>(wb); w[5] = qbcast_f<1>(wb);
        w[6] = qbcast_f<2>(wb); w[7] = qbcast_f<3>(wb);
        w[8] = w8;
        float d0 = 0.f;
        #pragma unroll
        for (int t = 0; t < NK; ++t) {
            d0 += w[t];
            #pragma unroll
            for (int k = 0; k < 8; ++k) num[k] += w[t] * (float)f[t][k];
        }
        #pragma unroll
        for (int k = 0; k < 8; ++k) den[k] = d0;
    } else {
        // broadcast d2 instead; per-channel sigma path (not hit by the bench)
        float d2v[NK];
        d2v[0] = qbcast_f<0>(d2a); d2v[1] = qbcast_f<1>(d2a);
        d2v[2] = qbcast_f<2>(d2a); d2v[3] = qbcast_f<3>(d2a);
        d2v[4] = qbcast_f<0>(d2b); d2v[5] = qbcast_f<1>(d2b);
        d2v[6] = qbcast_f<2>(d2b); d2v[7] = qbcast_f<3>(d2b);
        d2v[8] = d28;
        #pragma unroll
        for (int t = 0; t < NK; ++t) {
            #pragma unroll
            for (int k = 0; k < 8; ++k) {
                const float wk = __expf(-d2v[t] * s[k]);
                num[k] += wk * (float)f[t][k];
                den[k] += wk;
            }
        }
    }

    float* op = out + (size_t)point * D + h * 8;
    f4v o0, o1;
    o0[0] = num[0] / (den[0] + 1e-9f); o0[1] = num[1] / (den[1] + 1e-9f);
    o0[2] = num[2] / (den[2] + 1e-9f); o0[3] = num[3] / (den[3] + 1e-9f);
    o1[0] = num[4] / (den[4] + 1e-9f); o1[1] = num[5] / (den[5] + 1e-9f);
    o1[2] = num[6] / (den[6] + 1e-9f); o1[3] = num[7] / (den[7] + 1e-9f);
    // out is never re-read: NT stores keep 65 MB of write-allocate out of L2
    __builtin_nontemporal_store(o0, reinterpret_cast<f4v*>(op));
    __builtin_nontemporal_store(o1, reinterpret_cast<f4v*>(op + 4));
}

// ---------------- fallback: proven fp32 path (if ws too small) ---------------
__global__ __launch_bounds__(256) void projection_kernel_f32(
    const float* __restrict__ x,
    const float* __restrict__ coords_in,
    const float* __restrict__ coords_out,
    const float* __restrict__ sigma,
    const int*   __restrict__ nidx,
    float*       __restrict__ out)
{
    const int tid   = blockIdx.x * 256 + threadIdx.x;
    const int point = tid >> 3;
    const int q     = tid & 7;
    const int b     = point / PPB;
    const int cbase = b * N_IN;

    const float cox = coords_out[point];
    const float coy = coords_out[P + point];

    const float4 sg = *reinterpret_cast<const float4*>(sigma + q * 4);
    const float s0 = 1.0f / (2.0f * sg.x * sg.x);
    const float s1 = 1.0f / (2.0f * sg.y * sg.y);
    const float s2 = 1.0f / (2.0f * sg.z * sg.z);
    const float s3 = 1.0f / (2.0f * sg.w * sg.w);

    float4 num = make_float4(0.f, 0.f, 0.f, 0.f);
    float4 den = make_float4(0.f, 0.f, 0.f, 0.f);
    const int* __restrict__ ip = nidx + (size_t)point * NK;

    #pragma unroll
    for (int nk = 0; nk < NK; ++nk) {
        const int idx = ip[nk];
        const float cx = coords_in[cbase + idx];
        const float cy = coords_in[B * N_IN + cbase + idx];
        const float dx = cox - cx;
        const float dy = coy - cy;
        const float d2 = dx * dx + dy * dy;
        const float4 f = *reinterpret_cast<const float4*>(
            x + (size_t)(cbase + idx) * D + q * 4);
        const float w0 = __expf(-d2 * s0);
        const float w1 = __expf(-d2 * s1);
        const float w2 = __expf(-d2 * s2);
        const float w3 = __expf(-d2 * s3);
        num.x += w0 * f.x;  den.x += w0;
        num.y += w1 * f.y;  den.y += w1;
        num.z += w2 * f.z;  den.z += w2;
        num.w += w3 * f.w;  den.w += w3;
    }

    float4 o;
    o.x = num.x / (den.x + 1e-9f);
    o.y = num.y / (den.y + 1e-9f);
    o.z = num.z / (den.z + 1e-9f);
    o.w = num.w / (den.w + 1e-9f);
    *reinterpret_cast<float4*>(out + (size_t)point * D + q * 4) = o;
}

extern "C" void kernel_launch(void* const* d_in, const int* in_sizes, int n_in,
                              void* d_out, int out_size, void* d_ws, size_t ws_size,
                              hipStream_t stream) {
    const float* x      = (const float*)d_in[0];
    const float* cin    = (const float*)d_in[1];
    const float* cout_  = (const float*)d_in[2];
    const float* sigma  = (const float*)d_in[3];
    const int*   nidx   = (const int*)  d_in[4];
    float*       outp   = (float*)d_out;

    const int block = 256;

    const size_t xh_bytes = XTOT * sizeof(_Float16);            // 33.55 MB
    const size_t cp_bytes = (size_t)B * N_IN * sizeof(half2v);  //  2.10 MB

    if (ws_size >= xh_bytes + cp_bytes) {
        _Float16* xh = (_Float16*)d_ws;
        half2v*   cp = (half2v*)((char*)d_ws + xh_bytes);
        prep_kernel<<<(int)(XTOT / 8 / block), block, 0, stream>>>(x, xh, cin, cp);
        const int grid_main = (P * 4) / block;   // 8192
        projection_kernel_h<<<grid_main, block, 0, stream>>>(
            xh, cp, cout_, sigma, nidx, outp);
    } else {
        const int grid_main = (P * 8) / block;   // 16384
        projection_kernel_f32<<<grid_main, block, 0, stream>>>(
            x, cin, cout_, sigma, nidx, outp);
    }
}